// Round 6
// baseline (631.740 us; speedup 1.0000x reference)
//
#include <hip/hip_runtime.h>
#include <hip/hip_bf16.h>

typedef __bf16 bf16;
typedef __bf16 bf16x8 __attribute__((ext_vector_type(8)));
typedef float f32x4 __attribute__((ext_vector_type(4)));

#define LDST 264   // slab row stride in bf16 elems: 528 B (16B-aligned, 4-bank shift/row)

// ---------------- prep: transpose big weights -> bf16, PERMUTED slots, K-OUTER packed ----------------
// Logical col c -> slot ns = (c&~31) | (c odd ? 16+(c&31)/2 : (c&31)/2)   (permute within 32-groups)
// Storage: wpk[k>>3][slot][k&7]  (elem = (k>>3)*2048 + slot*8 + (k&7))
// -> per (kk,quad) the 16 B-frags of a wave are one contiguous 4KB region (imm-offset addressing,
//    coalesced 256B runs, all waves hit the same region -> L1/L2 reuse).
__global__ void transpose_all(const float* __restrict__ w0, const float* __restrict__ w1,
                              const float* __restrict__ w2, const float* __restrict__ w3,
                              bf16* __restrict__ out)
{
    __shared__ float tile[64][65];
    const int mz  = blockIdx.z;             // 0..23 = mat*6 + level
    const int mat = mz / 6;
    const float* srcs[4] = {w0, w1, w2, w3};
    const float* src = srcs[mat] + (size_t)(mz % 6) * 65536;
    bf16* dst = out + (size_t)mz * 65536;
    const int k0 = blockIdx.x * 64;
    const int n0 = blockIdx.y * 64;
    const int tx = threadIdx.x & 63, ty = threadIdx.x >> 6;
#pragma unroll
    for (int i = ty; i < 64; i += 4)
        tile[i][tx] = src[(size_t)(k0 + i) * 256 + n0 + tx];
    __syncthreads();
#pragma unroll
    for (int i = ty; i < 64; i += 4) {
        int n  = n0 + i;
        int o  = n & 31;
        int ns = (n & ~31) | ((o & 1) ? 16 + (o >> 1) : (o >> 1));
        int k  = k0 + tx;
        dst[(size_t)(k >> 3) * 2048 + ns * 8 + (k & 7)] = (bf16)tile[tx][i];
    }
}

// ---------------- prep: [6][256][10] -> [6][16][256] bf16, transposed + zero-padded (both w3s) ----------------
__global__ void prep_small(const float* __restrict__ cw3, const float* __restrict__ rw3,
                           bf16* __restrict__ outc, bf16* __restrict__ outr)
{
    int idx = blockIdx.x * 256 + threadIdx.x;  // 0..49151
    const float* w = (idx < 24576) ? cw3 : rw3;
    bf16* o = (idx < 24576) ? outc : outr;
    int j = (idx < 24576) ? idx : idx - 24576;
    int k = j & 255;
    int n = (j >> 8) & 15;
    int l = j >> 12;
    float v = (n < 10) ? w[((size_t)l * 256 + k) * 10 + n] : 0.0f;
    o[j] = (bf16)v;
}

// ---------------- helpers ----------------
__device__ __forceinline__ unsigned int pack2(float lo, float hi)
{
    union { bf16 h[2]; unsigned int u; } p;
    p.h[0] = (bf16)lo; p.h[1] = (bf16)hi;
    return p.u;
}

// VALU-pipe lane-reduce step: x += x[dpp-permuted lane]
template<int CTRL>
__device__ __forceinline__ float dppadd(float x)
{
    int y = __builtin_amdgcn_update_dpp(0, __float_as_int(x), CTRL, 0xF, 0xF, true);
    return x + __int_as_float(y);
}
// full sum across the 16-lane DPP row (= one quad); result broadcast to all 16 lanes
__device__ __forceinline__ float dppsum16(float x)
{
    x = dppadd<0xB1>(x);   // quad_perm [1,0,3,2]
    x = dppadd<0x4E>(x);   // quad_perm [2,3,0,1]
    x = dppadd<0x141>(x);  // row_half_mirror
    x = dppadd<0x140>(x);  // row_mirror
    return x;
}

// stage 32 rows of h (fp32 global) -> bf16 slab; wave-private, no barrier
__device__ __forceinline__ void stage_h(bf16* slab, const float* __restrict__ hs,
                                        int l, int row0w, int lane)
{
#pragma unroll 4
    for (int ri = 0; ri < 32; ri++) {
        const int r = row0w + ri;
        const int b = r / 900;
        const int q = r - b * 900;
        const float4* src = (const float4*)(hs + (((size_t)l * 900 + q) * 32 + b) * 256);
        float4 vv = src[lane];
        union { bf16 h[4]; uint2 u; } pk;
        pk.h[0] = (bf16)vv.x; pk.h[1] = (bf16)vv.y; pk.h[2] = (bf16)vv.z; pk.h[3] = (bf16)vv.w;
        *(uint2*)&slab[ri * LDST + lane * 4] = pk.u;
    }
}

// full-row GEMM, M=32 per wave: 32 rows x 256 cols, acc[m][16 nt].
// Each B-frag load feeds TWO MFMAs (m=0,1) -> halves B-bytes/FLOP vs M=16.
__device__ __forceinline__ void gemmFR32(const bf16* slab, const bf16* __restrict__ wt,
                                         int lane, f32x4 acc[2][16])
{
    const int quad = lane >> 4, lx = lane & 15;
#pragma unroll
    for (int m = 0; m < 2; m++)
#pragma unroll
        for (int nt = 0; nt < 16; nt++)
            acc[m][nt] = f32x4{0.f, 0.f, 0.f, 0.f};
    const bf16* base = wt + (size_t)quad * 2048 + lx * 8;
#pragma unroll
    for (int kk = 0; kk < 8; kk++) {
        bf16x8 a0 = *(const bf16x8*)&slab[lx * LDST + kk * 32 + quad * 8];
        bf16x8 a1 = *(const bf16x8*)&slab[(16 + lx) * LDST + kk * 32 + quad * 8];
        const bf16* bp = base + kk * 8192;
        bf16x8 bfrag[16];
#pragma unroll
        for (int nt = 0; nt < 16; nt++)
            bfrag[nt] = *(const bf16x8*)(bp + nt * 128);
#pragma unroll
        for (int nt = 0; nt < 16; nt++) {
            acc[0][nt] = __builtin_amdgcn_mfma_f32_16x16x32_bf16(a0, bfrag[nt], acc[0][nt], 0, 0, 0);
            acc[1][nt] = __builtin_amdgcn_mfma_f32_16x16x32_bf16(a1, bfrag[nt], acc[1][nt], 0, 0, 0);
        }
    }
}

// 16x256 @ 256x16 (small layers; weights [slot][256], unpermuted)
__device__ __forceinline__ f32x4 gemm16(const bf16* slab, const bf16* __restrict__ wt,
                                        int mrow0, int lane)
{
    const int quad = lane >> 4, lx = lane & 15;
    f32x4 acc = f32x4{0.f, 0.f, 0.f, 0.f};
#pragma unroll
    for (int kk = 0; kk < 8; kk++) {
        const int k0 = kk * 32 + quad * 8;
        bf16x8 a = *(const bf16x8*)&slab[(mrow0 + lx) * LDST + k0];
        bf16x8 b = *(const bf16x8*)&wt[lx * 256 + k0];
        acc = __builtin_amdgcn_mfma_f32_16x16x32_bf16(a, b, acc, 0, 0, 0);
    }
    return acc;
}

// ---- per-m epilogues: only ONE m-tile's 64 floats need arch VGPRs at a time (the other
// m-tile's accumulator can stay in AGPRs) — this is what keeps us under the arch-reg budget ----

// wave-local LN over one m-tile acc16[16]: bias add, stats (in-reg nt-sum + dppsum16), norm+relu
__device__ __forceinline__ void ln_epi_m(f32x4 acc16[16], const float* __restrict__ bias,
                                         const float* __restrict__ g, const float* __restrict__ bb,
                                         int lane)
{
    const int lx = lane & 15;
    float s[4] = {0.f, 0.f, 0.f, 0.f}, ss[4] = {0.f, 0.f, 0.f, 0.f};
#pragma unroll
    for (int sg = 0; sg < 8; sg++) {
        const float2 bv = *(const float2*)&bias[sg * 32 + 2 * lx];
#pragma unroll
        for (int r = 0; r < 4; r++) {
            float a0 = acc16[2 * sg][r] + bv.x;
            float a1 = acc16[2 * sg + 1][r] + bv.y;
            acc16[2 * sg][r] = a0; acc16[2 * sg + 1][r] = a1;
            s[r]  += a0 + a1;
            ss[r] += a0 * a0 + a1 * a1;
        }
    }
    float mean[4], rstd[4];
#pragma unroll
    for (int r = 0; r < 4; r++) {
        float st  = dppsum16(s[r]);
        float sst = dppsum16(ss[r]);
        mean[r] = st * (1.f / 256.f);
        float var = sst * (1.f / 256.f) - mean[r] * mean[r];
        rstd[r] = rsqrtf(var + 1e-5f);
    }
#pragma unroll
    for (int sg = 0; sg < 8; sg++) {
        const float2 gv  = *(const float2*)&g[sg * 32 + 2 * lx];
        const float2 bv2 = *(const float2*)&bb[sg * 32 + 2 * lx];
#pragma unroll
        for (int r = 0; r < 4; r++) {
            acc16[2 * sg][r]     = fmaxf((acc16[2 * sg][r]     - mean[r]) * rstd[r] * gv.x + bv2.x, 0.f);
            acc16[2 * sg + 1][r] = fmaxf((acc16[2 * sg + 1][r] - mean[r]) * rstd[r] * gv.y + bv2.y, 0.f);
        }
    }
}

__device__ __forceinline__ void bias_epi_m(f32x4 acc16[16], const float* __restrict__ bias, int lane)
{
    const int lx = lane & 15;
#pragma unroll
    for (int sg = 0; sg < 8; sg++) {
        const float2 bv = *(const float2*)&bias[sg * 32 + 2 * lx];
#pragma unroll
        for (int r = 0; r < 4; r++) {
            acc16[2 * sg][r]     = fmaxf(acc16[2 * sg][r]     + bv.x, 0.f);
            acc16[2 * sg + 1][r] = fmaxf(acc16[2 * sg + 1][r] + bv.y, 0.f);
        }
    }
}

// shuffle-free slab store for one m-tile: lane lx owns logical cols (32sg+2lx, 32sg+2lx+1);
// wave-order makes in-place reuse safe (same-wave DS ops retire in order), no barrier.
__device__ __forceinline__ void store_slab_m(bf16* slab, int lane, const f32x4 acc16[16], int m)
{
    const int quad = lane >> 4, lx = lane & 15;
#pragma unroll
    for (int sg = 0; sg < 8; sg++)
#pragma unroll
        for (int r = 0; r < 4; r++)
            *(unsigned int*)&slab[(m * 16 + quad * 4 + r) * LDST + sg * 32 + 2 * lx] =
                pack2(acc16[2 * sg][r], acc16[2 * sg + 1][r]);
}

// ---------------- main fused head kernel: ZERO block barriers, 32 rows per wave ----------------
// launch_bounds (256,1): VGPR cap 512 (measured toolchain semantics R1-R5: cap = 512 / waves-per-SIMD
// implied by arg2 blocks/CU). (256,2) capped arch regs at 128 -> the monolithic epilogue spilled
// (R5: WRITE 266 MB). Per-m epilogue + relaxed cap keeps arch-live ~64+temps. LDS 67.6 KB -> 2 blocks/CU.
__global__ __launch_bounds__(256, 1) void head_kernel(
    const float* __restrict__ hs, const float* __restrict__ init_ref,
    const float* __restrict__ inter_ref,
    const bf16* __restrict__ cw1t, const bf16* __restrict__ cw2t,
    const bf16* __restrict__ rw1t, const bf16* __restrict__ rw2t,
    const bf16* __restrict__ cw3t, const bf16* __restrict__ rw3t,
    const float* __restrict__ cb1, const float* __restrict__ g1, const float* __restrict__ b1,
    const float* __restrict__ cb2, const float* __restrict__ g2, const float* __restrict__ b2,
    const float* __restrict__ cb3,
    const float* __restrict__ rb1, const float* __restrict__ rb2, const float* __restrict__ rb3,
    float* __restrict__ out)
{
    __shared__ __align__(16) bf16 slabs[4][32 * LDST];   // 16.9 KB per wave, private

    const int l     = blockIdx.y;
    const int tid   = threadIdx.x;
    const int wave  = tid >> 6;
    const int lane  = tid & 63;
    const int quad  = lane >> 4;
    const int lx    = lane & 15;
    const int row0w = blockIdx.x * 128 + wave * 32;      // wave's first logical row (within level l)
    bf16* slab = slabs[wave];

    f32x4 acc[2][16];

    // ===== stage h, cls1: x1 = relu(LN(h@cw1+cb1)) -> slab (in place over h) =====
    stage_h(slab, hs, l, row0w, lane);
    gemmFR32(slab, cw1t + (size_t)l * 65536, lane, acc);
    ln_epi_m(acc[0], cb1 + l * 256, g1 + l * 256, b1 + l * 256, lane);
    store_slab_m(slab, lane, acc[0], 0);
    ln_epi_m(acc[1], cb1 + l * 256, g1 + l * 256, b1 + l * 256, lane);
    store_slab_m(slab, lane, acc[1], 1);

    // ===== cls2: x2 = relu(LN(x1@cw2+cb2)) -> slab =====
    gemmFR32(slab, cw2t + (size_t)l * 65536, lane, acc);
    ln_epi_m(acc[0], cb2 + l * 256, g2 + l * 256, b2 + l * 256, lane);
    store_slab_m(slab, lane, acc[0], 0);
    ln_epi_m(acc[1], cb2 + l * 256, g2 + l * 256, b2 + l * 256, lane);
    store_slab_m(slab, lane, acc[1], 1);

    // ===== cls3: out_cls = x2@cw3+cb3 =====
#pragma unroll
    for (int m = 0; m < 2; m++) {
        f32x4 c = gemm16(slab, cw3t + (size_t)l * 4096, m * 16, lane);
        if (lx < 10) {
            const float bv = cb3[l * 10 + lx];
#pragma unroll
            for (int r = 0; r < 4; r++) {
                int row = row0w + m * 16 + quad * 4 + r;
                out[((size_t)l * 28800 + row) * 10 + lx] = c[r] + bv;
            }
        }
    }

    // ===== re-stage h (L2/L3-resident), reg1: y1 = relu(h@rw1+rb1) -> slab =====
    stage_h(slab, hs, l, row0w, lane);
    gemmFR32(slab, rw1t + (size_t)l * 65536, lane, acc);
    bias_epi_m(acc[0], rb1 + l * 256, lane);
    store_slab_m(slab, lane, acc[0], 0);
    bias_epi_m(acc[1], rb1 + l * 256, lane);
    store_slab_m(slab, lane, acc[1], 1);

    // ===== reg2: y2 = relu(y1@rw2+rb2) -> slab =====
    gemmFR32(slab, rw2t + (size_t)l * 65536, lane, acc);
    bias_epi_m(acc[0], rb2 + l * 256, lane);
    store_slab_m(slab, lane, acc[0], 0);
    bias_epi_m(acc[1], rb2 + l * 256, lane);
    store_slab_m(slab, lane, acc[1], 1);

    // ===== reg3: tmp = y2@rw3+rb3 -> coord transform -> out =====
#pragma unroll
    for (int m = 0; m < 2; m++) {
        f32x4 t = gemm16(slab, rw3t + (size_t)l * 4096, m * 16, lane);
        if (lx < 10) {
            const float bv = rb3[l * 10 + lx];
            const float* refp = (l == 0) ? init_ref : (inter_ref + (size_t)(l - 1) * 28800 * 3);
#pragma unroll
            for (int r = 0; r < 4; r++) {
                int row = row0w + m * 16 + quad * 4 + r;
                float vv = t[r] + bv;
                float o;
                if (lx == 0 || lx == 1 || lx == 4) {
                    int rc = (lx == 4) ? 2 : lx;
                    float x = refp[(size_t)row * 3 + rc];
                    x = fminf(fmaxf(x, 0.f), 1.f);
                    float x1 = fmaxf(x, 1e-5f);
                    float x2 = fmaxf(1.f - x, 1e-5f);
                    float ris = logf(x1) - logf(x2);
                    float sg = 1.f / (1.f + expf(-(vv + ris)));
                    o = (lx == 4) ? (sg * 8.f - 5.f) : (sg * 102.4f - 51.2f);
                } else {
                    o = vv;
                }
                out[(size_t)(6 + l) * 28800 * 10 + (size_t)row * 10 + lx] = o;
            }
        }
    }
}

extern "C" void kernel_launch(void* const* d_in, const int* in_sizes, int n_in,
                              void* d_out, int out_size, void* d_ws, size_t ws_size,
                              hipStream_t stream)
{
    const float* hs        = (const float*)d_in[0];
    const float* init_ref  = (const float*)d_in[1];
    const float* inter_ref = (const float*)d_in[2];
    const float* cls_w1    = (const float*)d_in[3];
    const float* cls_b1    = (const float*)d_in[4];
    const float* ln1_g     = (const float*)d_in[5];
    const float* ln1_b     = (const float*)d_in[6];
    const float* cls_w2    = (const float*)d_in[7];
    const float* cls_b2    = (const float*)d_in[8];
    const float* ln2_g     = (const float*)d_in[9];
    const float* ln2_b     = (const float*)d_in[10];
    const float* cls_w3    = (const float*)d_in[11];
    const float* cls_b3    = (const float*)d_in[12];
    const float* reg_w1    = (const float*)d_in[13];
    const float* reg_b1    = (const float*)d_in[14];
    const float* reg_w2    = (const float*)d_in[15];
    const float* reg_b2    = (const float*)d_in[16];
    const float* reg_w3    = (const float*)d_in[17];
    const float* reg_b3    = (const float*)d_in[18];

    bf16* ws   = (bf16*)d_ws;
    bf16* cw1t = ws;                  // 4 contiguous 6*65536 regions (K-outer packed)
    bf16* cw2t = cw1t + 393216;
    bf16* rw1t = cw2t + 393216;
    bf16* rw2t = rw1t + 393216;
    bf16* cw3t = rw2t + 393216;       // 6*16*256
    bf16* rw3t = cw3t + 24576;

    transpose_all<<<dim3(4, 4, 24), 256, 0, stream>>>(cls_w1, cls_w2, reg_w1, reg_w2, cw1t);
    prep_small<<<192, 256, 0, stream>>>(cls_w3, reg_w3, cw3t, rw3t);

    head_kernel<<<dim3(225, 6), 256, 0, stream>>>(
        hs, init_ref, inter_ref,
        cw1t, cw2t, rw1t, rw2t, cw3t, rw3t,
        cls_b1, ln1_g, ln1_b, cls_b2, ln2_g, ln2_b, cls_b3,
        reg_b1, reg_b2, reg_b3, (float*)d_out);
}

// Round 7
// 491.102 us; speedup vs baseline: 1.2864x; 1.2864x over previous
//
#include <hip/hip_runtime.h>
#include <hip/hip_bf16.h>

typedef __bf16 bf16;
typedef __bf16 bf16x8 __attribute__((ext_vector_type(8)));
typedef float f32x4 __attribute__((ext_vector_type(4)));

#define LDST 264   // slab row stride in bf16 elems: 528 B (16B-aligned, 4-bank shift/row)

// ---------------- prep: transpose big weights -> bf16, PERMUTED slots, K-OUTER packed ----------------
// Logical col c -> slot ns = (c&~31) | (c odd ? 16+(c&31)/2 : (c&31)/2)   (permute within 32-groups)
// Storage: wpk[k>>3][slot][k&7]  (elem = (k>>3)*2048 + slot*8 + (k&7))
// -> per (kk,quad) the 16 B-frags of a wave are one contiguous 4KB region (imm-offset addressing,
//    coalesced 256B runs, all waves hit the same region -> L1/L2 reuse).
__global__ void transpose_all(const float* __restrict__ w0, const float* __restrict__ w1,
                              const float* __restrict__ w2, const float* __restrict__ w3,
                              bf16* __restrict__ out)
{
    __shared__ float tile[64][65];
    const int mz  = blockIdx.z;             // 0..23 = mat*6 + level
    const int mat = mz / 6;
    const float* srcs[4] = {w0, w1, w2, w3};
    const float* src = srcs[mat] + (size_t)(mz % 6) * 65536;
    bf16* dst = out + (size_t)mz * 65536;
    const int k0 = blockIdx.x * 64;
    const int n0 = blockIdx.y * 64;
    const int tx = threadIdx.x & 63, ty = threadIdx.x >> 6;
#pragma unroll
    for (int i = ty; i < 64; i += 4)
        tile[i][tx] = src[(size_t)(k0 + i) * 256 + n0 + tx];
    __syncthreads();
#pragma unroll
    for (int i = ty; i < 64; i += 4) {
        int n  = n0 + i;
        int o  = n & 31;
        int ns = (n & ~31) | ((o & 1) ? 16 + (o >> 1) : (o >> 1));
        int k  = k0 + tx;
        dst[(size_t)(k >> 3) * 2048 + ns * 8 + (k & 7)] = (bf16)tile[tx][i];
    }
}

// ---------------- prep: [6][256][10] -> [6][16][256] bf16, transposed + zero-padded (both w3s) ----------------
__global__ void prep_small(const float* __restrict__ cw3, const float* __restrict__ rw3,
                           bf16* __restrict__ outc, bf16* __restrict__ outr)
{
    int idx = blockIdx.x * 256 + threadIdx.x;  // 0..49151
    const float* w = (idx < 24576) ? cw3 : rw3;
    bf16* o = (idx < 24576) ? outc : outr;
    int j = (idx < 24576) ? idx : idx - 24576;
    int k = j & 255;
    int n = (j >> 8) & 15;
    int l = j >> 12;
    float v = (n < 10) ? w[((size_t)l * 256 + k) * 10 + n] : 0.0f;
    o[j] = (bf16)v;
}

// ---------------- helpers ----------------
__device__ __forceinline__ unsigned int pack2(float lo, float hi)
{
    union { bf16 h[2]; unsigned int u; } p;
    p.h[0] = (bf16)lo; p.h[1] = (bf16)hi;
    return p.u;
}

// VALU-pipe lane-reduce step: x += x[dpp-permuted lane]
template<int CTRL>
__device__ __forceinline__ float dppadd(float x)
{
    int y = __builtin_amdgcn_update_dpp(0, __float_as_int(x), CTRL, 0xF, 0xF, true);
    return x + __int_as_float(y);
}
// full sum across the 16-lane DPP row (= one quad); result broadcast to all 16 lanes
__device__ __forceinline__ float dppsum16(float x)
{
    x = dppadd<0xB1>(x);   // quad_perm [1,0,3,2]
    x = dppadd<0x4E>(x);   // quad_perm [2,3,0,1]
    x = dppadd<0x141>(x);  // row_half_mirror
    x = dppadd<0x140>(x);  // row_mirror
    return x;
}

// stage 32 rows of h (fp32 global) -> bf16 slab; wave-private, no barrier
__device__ __forceinline__ void stage_h(bf16* slab, const float* __restrict__ hs,
                                        int l, int row0w, int lane)
{
#pragma unroll 4
    for (int ri = 0; ri < 32; ri++) {
        const int r = row0w + ri;
        const int b = r / 900;
        const int q = r - b * 900;
        const float4* src = (const float4*)(hs + (((size_t)l * 900 + q) * 32 + b) * 256);
        float4 vv = src[lane];
        union { bf16 h[4]; uint2 u; } pk;
        pk.h[0] = (bf16)vv.x; pk.h[1] = (bf16)vv.y; pk.h[2] = (bf16)vv.z; pk.h[3] = (bf16)vv.w;
        *(uint2*)&slab[ri * LDST + lane * 4] = pk.u;
    }
}

// full-row GEMM, M=32 per wave: 32 rows x 256 cols, acc[m][16 nt].
// Each B-frag load feeds TWO MFMAs -> halves B-bytes/FLOP vs M=16.
// B loaded in chunks of 8 frags (32 arch VGPRs live) to keep non-acc arch pressure ~60 regs,
// so the 128-arch / 128-AGPR split under the (256,2) total-256 cap holds without spill.
__device__ __forceinline__ void gemmFR32(const bf16* slab, const bf16* __restrict__ wt,
                                         int lane, f32x4 acc[2][16])
{
    const int quad = lane >> 4, lx = lane & 15;
#pragma unroll
    for (int m = 0; m < 2; m++)
#pragma unroll
        for (int nt = 0; nt < 16; nt++)
            acc[m][nt] = f32x4{0.f, 0.f, 0.f, 0.f};
    const bf16* base = wt + (size_t)quad * 2048 + lx * 8;
#pragma unroll
    for (int kk = 0; kk < 8; kk++) {
        bf16x8 a0 = *(const bf16x8*)&slab[lx * LDST + kk * 32 + quad * 8];
        bf16x8 a1 = *(const bf16x8*)&slab[(16 + lx) * LDST + kk * 32 + quad * 8];
        const bf16* bp = base + kk * 8192;
#pragma unroll
        for (int c = 0; c < 2; c++) {
            bf16x8 bfrag[8];
#pragma unroll
            for (int j = 0; j < 8; j++)
                bfrag[j] = *(const bf16x8*)(bp + (c * 8 + j) * 128);
#pragma unroll
            for (int j = 0; j < 8; j++) {
                acc[0][c * 8 + j] = __builtin_amdgcn_mfma_f32_16x16x32_bf16(a0, bfrag[j], acc[0][c * 8 + j], 0, 0, 0);
                acc[1][c * 8 + j] = __builtin_amdgcn_mfma_f32_16x16x32_bf16(a1, bfrag[j], acc[1][c * 8 + j], 0, 0, 0);
            }
        }
    }
}

// 16x256 @ 256x16 (small layers; weights [slot][256], unpermuted)
__device__ __forceinline__ f32x4 gemm16(const bf16* slab, const bf16* __restrict__ wt,
                                        int mrow0, int lane)
{
    const int quad = lane >> 4, lx = lane & 15;
    f32x4 acc = f32x4{0.f, 0.f, 0.f, 0.f};
#pragma unroll
    for (int kk = 0; kk < 8; kk++) {
        const int k0 = kk * 32 + quad * 8;
        bf16x8 a = *(const bf16x8*)&slab[(mrow0 + lx) * LDST + k0];
        bf16x8 b = *(const bf16x8*)&wt[lx * 256 + k0];
        acc = __builtin_amdgcn_mfma_f32_16x16x32_bf16(a, b, acc, 0, 0, 0);
    }
    return acc;
}

// ---- per-m epilogues: only ONE m-tile's 64 floats need arch VGPRs at a time (the other
// m-tile's accumulator stays in AGPRs) — keeps arch-live under the 128-arch budget ----

// wave-local LN over one m-tile acc16[16]: bias add, stats (in-reg nt-sum + dppsum16), norm+relu
__device__ __forceinline__ void ln_epi_m(f32x4 acc16[16], const float* __restrict__ bias,
                                         const float* __restrict__ g, const float* __restrict__ bb,
                                         int lane)
{
    const int lx = lane & 15;
    float s[4] = {0.f, 0.f, 0.f, 0.f}, ss[4] = {0.f, 0.f, 0.f, 0.f};
#pragma unroll
    for (int sg = 0; sg < 8; sg++) {
        const float2 bv = *(const float2*)&bias[sg * 32 + 2 * lx];
#pragma unroll
        for (int r = 0; r < 4; r++) {
            float a0 = acc16[2 * sg][r] + bv.x;
            float a1 = acc16[2 * sg + 1][r] + bv.y;
            acc16[2 * sg][r] = a0; acc16[2 * sg + 1][r] = a1;
            s[r]  += a0 + a1;
            ss[r] += a0 * a0 + a1 * a1;
        }
    }
    float mean[4], rstd[4];
#pragma unroll
    for (int r = 0; r < 4; r++) {
        float st  = dppsum16(s[r]);
        float sst = dppsum16(ss[r]);
        mean[r] = st * (1.f / 256.f);
        float var = sst * (1.f / 256.f) - mean[r] * mean[r];
        rstd[r] = rsqrtf(var + 1e-5f);
    }
#pragma unroll
    for (int sg = 0; sg < 8; sg++) {
        const float2 gv  = *(const float2*)&g[sg * 32 + 2 * lx];
        const float2 bv2 = *(const float2*)&bb[sg * 32 + 2 * lx];
#pragma unroll
        for (int r = 0; r < 4; r++) {
            acc16[2 * sg][r]     = fmaxf((acc16[2 * sg][r]     - mean[r]) * rstd[r] * gv.x + bv2.x, 0.f);
            acc16[2 * sg + 1][r] = fmaxf((acc16[2 * sg + 1][r] - mean[r]) * rstd[r] * gv.y + bv2.y, 0.f);
        }
    }
}

__device__ __forceinline__ void bias_epi_m(f32x4 acc16[16], const float* __restrict__ bias, int lane)
{
    const int lx = lane & 15;
#pragma unroll
    for (int sg = 0; sg < 8; sg++) {
        const float2 bv = *(const float2*)&bias[sg * 32 + 2 * lx];
#pragma unroll
        for (int r = 0; r < 4; r++) {
            acc16[2 * sg][r]     = fmaxf(acc16[2 * sg][r]     + bv.x, 0.f);
            acc16[2 * sg + 1][r] = fmaxf(acc16[2 * sg + 1][r] + bv.y, 0.f);
        }
    }
}

// shuffle-free slab store for one m-tile: lane lx owns logical cols (32sg+2lx, 32sg+2lx+1);
// wave-order makes in-place reuse safe (same-wave DS ops retire in order), no barrier.
__device__ __forceinline__ void store_slab_m(bf16* slab, int lane, const f32x4 acc16[16], int m)
{
    const int quad = lane >> 4, lx = lane & 15;
#pragma unroll
    for (int sg = 0; sg < 8; sg++)
#pragma unroll
        for (int r = 0; r < 4; r++)
            *(unsigned int*)&slab[(m * 16 + quad * 4 + r) * LDST + sg * 32 + 2 * lx] =
                pack2(acc16[2 * sg][r], acc16[2 * sg + 1][r]);
}

// ---------------- main fused head kernel: ZERO block barriers, 32 rows per wave ----------------
// Register model (measured R1-R6): pool = 512 regs/SIMD; launch_bounds arg2 -> total-reg cap
// (arch+AGPR): (256,2) -> 256 total = 128 arch + 128 acc-AGPR, 2 waves/SIMD. R5 spilled under this
// cap because the monolithic epilogue needed >128 arch live; per-m epilogue (~64+temps) + chunked
// B-window (~60 in gemm) fits. (256,1) let arch balloon to 224 -> 352 total -> 1 wave/SIMD (R6).
__global__ __launch_bounds__(256, 2) void head_kernel(
    const float* __restrict__ hs, const float* __restrict__ init_ref,
    const float* __restrict__ inter_ref,
    const bf16* __restrict__ cw1t, const bf16* __restrict__ cw2t,
    const bf16* __restrict__ rw1t, const bf16* __restrict__ rw2t,
    const bf16* __restrict__ cw3t, const bf16* __restrict__ rw3t,
    const float* __restrict__ cb1, const float* __restrict__ g1, const float* __restrict__ b1,
    const float* __restrict__ cb2, const float* __restrict__ g2, const float* __restrict__ b2,
    const float* __restrict__ cb3,
    const float* __restrict__ rb1, const float* __restrict__ rb2, const float* __restrict__ rb3,
    float* __restrict__ out)
{
    __shared__ __align__(16) bf16 slabs[4][32 * LDST];   // 16.9 KB per wave, private

    const int l     = blockIdx.y;
    const int tid   = threadIdx.x;
    const int wave  = tid >> 6;
    const int lane  = tid & 63;
    const int quad  = lane >> 4;
    const int lx    = lane & 15;
    const int row0w = blockIdx.x * 128 + wave * 32;      // wave's first logical row (within level l)
    bf16* slab = slabs[wave];

    f32x4 acc[2][16];

    // ===== stage h, cls1: x1 = relu(LN(h@cw1+cb1)) -> slab (in place over h) =====
    stage_h(slab, hs, l, row0w, lane);
    gemmFR32(slab, cw1t + (size_t)l * 65536, lane, acc);
    ln_epi_m(acc[0], cb1 + l * 256, g1 + l * 256, b1 + l * 256, lane);
    store_slab_m(slab, lane, acc[0], 0);
    ln_epi_m(acc[1], cb1 + l * 256, g1 + l * 256, b1 + l * 256, lane);
    store_slab_m(slab, lane, acc[1], 1);

    // ===== cls2: x2 = relu(LN(x1@cw2+cb2)) -> slab =====
    gemmFR32(slab, cw2t + (size_t)l * 65536, lane, acc);
    ln_epi_m(acc[0], cb2 + l * 256, g2 + l * 256, b2 + l * 256, lane);
    store_slab_m(slab, lane, acc[0], 0);
    ln_epi_m(acc[1], cb2 + l * 256, g2 + l * 256, b2 + l * 256, lane);
    store_slab_m(slab, lane, acc[1], 1);

    // ===== cls3: out_cls = x2@cw3+cb3 =====
#pragma unroll
    for (int m = 0; m < 2; m++) {
        f32x4 c = gemm16(slab, cw3t + (size_t)l * 4096, m * 16, lane);
        if (lx < 10) {
            const float bv = cb3[l * 10 + lx];
#pragma unroll
            for (int r = 0; r < 4; r++) {
                int row = row0w + m * 16 + quad * 4 + r;
                out[((size_t)l * 28800 + row) * 10 + lx] = c[r] + bv;
            }
        }
    }

    // ===== re-stage h (L2/L3-resident), reg1: y1 = relu(h@rw1+rb1) -> slab =====
    stage_h(slab, hs, l, row0w, lane);
    gemmFR32(slab, rw1t + (size_t)l * 65536, lane, acc);
    bias_epi_m(acc[0], rb1 + l * 256, lane);
    store_slab_m(slab, lane, acc[0], 0);
    bias_epi_m(acc[1], rb1 + l * 256, lane);
    store_slab_m(slab, lane, acc[1], 1);

    // ===== reg2: y2 = relu(y1@rw2+rb2) -> slab =====
    gemmFR32(slab, rw2t + (size_t)l * 65536, lane, acc);
    bias_epi_m(acc[0], rb2 + l * 256, lane);
    store_slab_m(slab, lane, acc[0], 0);
    bias_epi_m(acc[1], rb2 + l * 256, lane);
    store_slab_m(slab, lane, acc[1], 1);

    // ===== reg3: tmp = y2@rw3+rb3 -> coord transform -> out =====
#pragma unroll
    for (int m = 0; m < 2; m++) {
        f32x4 t = gemm16(slab, rw3t + (size_t)l * 4096, m * 16, lane);
        if (lx < 10) {
            const float bv = rb3[l * 10 + lx];
            const float* refp = (l == 0) ? init_ref : (inter_ref + (size_t)(l - 1) * 28800 * 3);
#pragma unroll
            for (int r = 0; r < 4; r++) {
                int row = row0w + m * 16 + quad * 4 + r;
                float vv = t[r] + bv;
                float o;
                if (lx == 0 || lx == 1 || lx == 4) {
                    int rc = (lx == 4) ? 2 : lx;
                    float x = refp[(size_t)row * 3 + rc];
                    x = fminf(fmaxf(x, 0.f), 1.f);
                    float x1 = fmaxf(x, 1e-5f);
                    float x2 = fmaxf(1.f - x, 1e-5f);
                    float ris = logf(x1) - logf(x2);
                    float sg = 1.f / (1.f + expf(-(vv + ris)));
                    o = (lx == 4) ? (sg * 8.f - 5.f) : (sg * 102.4f - 51.2f);
                } else {
                    o = vv;
                }
                out[(size_t)(6 + l) * 28800 * 10 + (size_t)row * 10 + lx] = o;
            }
        }
    }
}

extern "C" void kernel_launch(void* const* d_in, const int* in_sizes, int n_in,
                              void* d_out, int out_size, void* d_ws, size_t ws_size,
                              hipStream_t stream)
{
    const float* hs        = (const float*)d_in[0];
    const float* init_ref  = (const float*)d_in[1];
    const float* inter_ref = (const float*)d_in[2];
    const float* cls_w1    = (const float*)d_in[3];
    const float* cls_b1    = (const float*)d_in[4];
    const float* ln1_g     = (const float*)d_in[5];
    const float* ln1_b     = (const float*)d_in[6];
    const float* cls_w2    = (const float*)d_in[7];
    const float* cls_b2    = (const float*)d_in[8];
    const float* ln2_g     = (const float*)d_in[9];
    const float* ln2_b     = (const float*)d_in[10];
    const float* cls_w3    = (const float*)d_in[11];
    const float* cls_b3    = (const float*)d_in[12];
    const float* reg_w1    = (const float*)d_in[13];
    const float* reg_b1    = (const float*)d_in[14];
    const float* reg_w2    = (const float*)d_in[15];
    const float* reg_b2    = (const float*)d_in[16];
    const float* reg_w3    = (const float*)d_in[17];
    const float* reg_b3    = (const float*)d_in[18];

    bf16* ws   = (bf16*)d_ws;
    bf16* cw1t = ws;                  // 4 contiguous 6*65536 regions (K-outer packed)
    bf16* cw2t = cw1t + 393216;
    bf16* rw1t = cw2t + 393216;
    bf16* rw2t = rw1t + 393216;
    bf16* cw3t = rw2t + 393216;       // 6*16*256
    bf16* rw3t = cw3t + 24576;

    transpose_all<<<dim3(4, 4, 24), 256, 0, stream>>>(cls_w1, cls_w2, reg_w1, reg_w2, cw1t);
    prep_small<<<192, 256, 0, stream>>>(cls_w3, reg_w3, cw3t, rw3t);

    head_kernel<<<dim3(225, 6), 256, 0, stream>>>(
        hs, init_ref, inter_ref,
        cw1t, cw2t, rw1t, rw2t, cw3t, rw3t,
        cls_b1, ln1_g, ln1_b, cls_b2, ln2_g, ln2_b, cls_b3,
        reg_b1, reg_b2, reg_b3, (float*)d_out);
}